// Round 1
// baseline (554.049 us; speedup 1.0000x reference)
//
#include <hip/hip_runtime.h>
#include <math.h>

#define BATCH 16
#define CDIM 256
#define HW 9216
#define RDIM 32
#define KC 32
#define LDST 68   // LDS row stride (floats): keeps float4 alignment, spreads banks

// ---------------- K1: global average pool per (b,c) ----------------
__global__ __launch_bounds__(256) void pool_kernel(const float* __restrict__ x,
                                                   float* __restrict__ pooled) {
    int bc = blockIdx.x;                       // 0..B*C-1
    const float4* row4 = (const float4*)(x + (size_t)bc * HW);
    float s = 0.f;
    for (int i = threadIdx.x; i < HW / 4; i += 256) {
        float4 v = row4[i];
        s += v.x + v.y + v.z + v.w;
    }
    for (int off = 32; off > 0; off >>= 1) s += __shfl_down(s, off);
    __shared__ float red[4];
    if ((threadIdx.x & 63) == 0) red[threadIdx.x >> 6] = s;
    __syncthreads();
    if (threadIdx.x == 0)
        pooled[bc] = (red[0] + red[1] + red[2] + red[3]) * (1.0f / HW);
}

// ---------------- K2: SE MLP -> sigmoid gate ----------------
__global__ __launch_bounds__(256) void se_kernel(const float* __restrict__ pooled,
                                                 const float* __restrict__ w1,
                                                 const float* __restrict__ b1,
                                                 const float* __restrict__ w2,
                                                 const float* __restrict__ b2,
                                                 float* __restrict__ gate) {
    int b = blockIdx.x;
    int t = threadIdx.x;
    __shared__ float p[CDIM];
    __shared__ float hid[RDIM];
    p[t] = pooled[b * CDIM + t];
    __syncthreads();
    if (t < RDIM) {
        float s = b1[t];
        const float* wr = w1 + t * CDIM;
        for (int k = 0; k < CDIM; ++k) s = fmaf(wr[k], p[k], s);
        hid[t] = s > 0.f ? s : 0.f;
    }
    __syncthreads();
    float s = b2[t];
    const float* wr = w2 + t * RDIM;
    #pragma unroll
    for (int k = 0; k < RDIM; ++k) s = fmaf(wr[k], hid[k], s);
    gate[b * CDIM + t] = 1.0f / (1.0f + expf(-s));
}

// ---------------- K3: energy = v v^T  (split-K, atomic accumulate) ----------------
// grid: (16 tiles, BATCH, 4 splits); block 256. Tile 64x64, microtile 4x4.
__global__ __launch_bounds__(256) void gram_kernel(const float* __restrict__ x,
                                                   float* __restrict__ energy) {
    int tile  = blockIdx.x;            // 4x4 tiles of the 256x256 output
    int b     = blockIdx.y;
    int split = blockIdx.z;            // 0..3
    int c0 = (tile >> 2) * 64;
    int d0 = (tile & 3) * 64;
    const float* v = x + (size_t)b * CDIM * HW;

    __shared__ float As[KC][LDST];
    __shared__ float Bs[KC][LDST];

    int t  = threadIdx.x;
    int tx = t & 15, ty = t >> 4;
    int lrow = t >> 3;                 // 0..31
    int lk4  = (t & 7) * 4;            // 0..28

    float acc[4][4] = {};

    int kb = split * (HW / 4);
    int ke = kb + (HW / 4);
    for (int k0 = kb; k0 < ke; k0 += KC) {
        float4 a0 = *(const float4*)&v[(size_t)(c0 + lrow)      * HW + k0 + lk4];
        float4 a1 = *(const float4*)&v[(size_t)(c0 + lrow + 32) * HW + k0 + lk4];
        float4 b0 = *(const float4*)&v[(size_t)(d0 + lrow)      * HW + k0 + lk4];
        float4 b1 = *(const float4*)&v[(size_t)(d0 + lrow + 32) * HW + k0 + lk4];
        __syncthreads();
        As[lk4+0][lrow] = a0.x; As[lk4+1][lrow] = a0.y; As[lk4+2][lrow] = a0.z; As[lk4+3][lrow] = a0.w;
        As[lk4+0][lrow+32] = a1.x; As[lk4+1][lrow+32] = a1.y; As[lk4+2][lrow+32] = a1.z; As[lk4+3][lrow+32] = a1.w;
        Bs[lk4+0][lrow] = b0.x; Bs[lk4+1][lrow] = b0.y; Bs[lk4+2][lrow] = b0.z; Bs[lk4+3][lrow] = b0.w;
        Bs[lk4+0][lrow+32] = b1.x; Bs[lk4+1][lrow+32] = b1.y; Bs[lk4+2][lrow+32] = b1.z; Bs[lk4+3][lrow+32] = b1.w;
        __syncthreads();
        #pragma unroll
        for (int k = 0; k < KC; ++k) {
            float af[4], bf[4];
            *(float4*)af = *(const float4*)&As[k][ty * 4];
            *(float4*)bf = *(const float4*)&Bs[k][tx * 4];
            #pragma unroll
            for (int i = 0; i < 4; ++i)
                #pragma unroll
                for (int j = 0; j < 4; ++j)
                    acc[i][j] = fmaf(af[i], bf[j], acc[i][j]);
        }
    }
    #pragma unroll
    for (int i = 0; i < 4; ++i) {
        int c = c0 + ty * 4 + i;
        #pragma unroll
        for (int j = 0; j < 4; ++j) {
            int d = d0 + tx * 4 + j;
            atomicAdd(&energy[((size_t)b * CDIM + c) * CDIM + d], acc[i][j]);
        }
    }
}

// ---------------- K4: row softmax of (max-row - energy), in place ----------------
// attention[c,d] = exp(rowmin - e[c,d]) / sum  (identical to reference softmax)
__global__ __launch_bounds__(256) void softmax_kernel(float* __restrict__ energy) {
    int row = blockIdx.x;              // b*C + c
    float* e = energy + (size_t)row * CDIM;
    int t = threadIdx.x;
    float val = e[t];

    float m = val;
    for (int off = 32; off > 0; off >>= 1) m = fminf(m, __shfl_down(m, off));
    __shared__ float redm[4];
    if ((t & 63) == 0) redm[t >> 6] = m;
    __syncthreads();
    float rowmin = fminf(fminf(redm[0], redm[1]), fminf(redm[2], redm[3]));

    float p = expf(rowmin - val);
    float s = p;
    for (int off = 32; off > 0; off >>= 1) s += __shfl_down(s, off);
    __shared__ float reds[4];
    if ((t & 63) == 0) reds[t >> 6] = s;
    __syncthreads();
    float tot = reds[0] + reds[1] + reds[2] + reds[3];
    e[t] = p / tot;
}

// ---------------- K5: out = gamma * gate * (att @ v) + x ----------------
// grid: (144 n-tiles, 4 c-tiles, BATCH); block 256. Tile 64(c) x 64(n), K=256.
__global__ __launch_bounds__(256) void out_kernel(const float* __restrict__ att,
                                                  const float* __restrict__ x,
                                                  const float* __restrict__ gate,
                                                  const float* __restrict__ gammap,
                                                  float* __restrict__ out) {
    int n0 = blockIdx.x * 64;
    int c0 = blockIdx.y * 64;
    int b  = blockIdx.z;
    const float* v    = x   + (size_t)b * CDIM * HW;
    const float* attb = att + (size_t)b * CDIM * CDIM;

    __shared__ float As[KC][LDST];   // As[k][m] = att[c0+m][k0+k]
    __shared__ float Bs[KC][LDST];   // Bs[k][n] = v[k0+k][n0+n]

    int t  = threadIdx.x;
    int tx = t & 15, ty = t >> 4;
    int lrow = t >> 3;                 // A-load: 0..31
    int lk4  = (t & 7) * 4;
    int bk   = t >> 4;                 // B-load row 0..15
    int bn4  = (t & 15) * 4;

    float acc[4][4] = {};

    for (int k0 = 0; k0 < CDIM; k0 += KC) {
        float4 a0 = *(const float4*)&attb[(size_t)(c0 + lrow)      * CDIM + k0 + lk4];
        float4 a1 = *(const float4*)&attb[(size_t)(c0 + lrow + 32) * CDIM + k0 + lk4];
        float4 b0 = *(const float4*)&v[(size_t)(k0 + bk)      * HW + n0 + bn4];
        float4 b1 = *(const float4*)&v[(size_t)(k0 + bk + 16) * HW + n0 + bn4];
        __syncthreads();
        As[lk4+0][lrow] = a0.x; As[lk4+1][lrow] = a0.y; As[lk4+2][lrow] = a0.z; As[lk4+3][lrow] = a0.w;
        As[lk4+0][lrow+32] = a1.x; As[lk4+1][lrow+32] = a1.y; As[lk4+2][lrow+32] = a1.z; As[lk4+3][lrow+32] = a1.w;
        *(float4*)&Bs[bk][bn4]      = b0;
        *(float4*)&Bs[bk + 16][bn4] = b1;
        __syncthreads();
        #pragma unroll
        for (int k = 0; k < KC; ++k) {
            float af[4], bf[4];
            *(float4*)af = *(const float4*)&As[k][ty * 4];
            *(float4*)bf = *(const float4*)&Bs[k][tx * 4];
            #pragma unroll
            for (int i = 0; i < 4; ++i)
                #pragma unroll
                for (int j = 0; j < 4; ++j)
                    acc[i][j] = fmaf(af[i], bf[j], acc[i][j]);
        }
    }

    float gm = gammap[0];
    #pragma unroll
    for (int i = 0; i < 4; ++i) {
        int c = c0 + ty * 4 + i;
        float g = gm * gate[b * CDIM + c];
        size_t base = ((size_t)b * CDIM + c) * HW + n0 + tx * 4;
        float4 xv = *(const float4*)&x[base];
        float4 o;
        o.x = fmaf(acc[i][0], g, xv.x);
        o.y = fmaf(acc[i][1], g, xv.y);
        o.z = fmaf(acc[i][2], g, xv.z);
        o.w = fmaf(acc[i][3], g, xv.w);
        *(float4*)&out[base] = o;
    }
}

extern "C" void kernel_launch(void* const* d_in, const int* in_sizes, int n_in,
                              void* d_out, int out_size, void* d_ws, size_t ws_size,
                              hipStream_t stream) {
    const float* x     = (const float*)d_in[0];
    const float* gamma = (const float*)d_in[1];
    const float* w1    = (const float*)d_in[2];
    const float* b1    = (const float*)d_in[3];
    const float* w2    = (const float*)d_in[4];
    const float* b2    = (const float*)d_in[5];
    float* out = (float*)d_out;

    float* energy = (float*)d_ws;                                // B*C*C floats = 4 MB
    float* pooled = energy + (size_t)BATCH * CDIM * CDIM;        // B*C
    float* gate   = pooled + BATCH * CDIM;                       // B*C

    hipMemsetAsync(energy, 0, (size_t)BATCH * CDIM * CDIM * sizeof(float), stream);
    pool_kernel<<<BATCH * CDIM, 256, 0, stream>>>(x, pooled);
    se_kernel<<<BATCH, 256, 0, stream>>>(pooled, w1, b1, w2, b2, gate);
    gram_kernel<<<dim3(16, BATCH, 4), 256, 0, stream>>>(x, energy);
    softmax_kernel<<<BATCH * CDIM, 256, 0, stream>>>(energy);
    out_kernel<<<dim3(HW / 64, CDIM / 64, BATCH), 256, 0, stream>>>(energy, x, gate, gamma, out);
}

// Round 2
// 359.693 us; speedup vs baseline: 1.5403x; 1.5403x over previous
//
#include <hip/hip_runtime.h>
#include <math.h>

#define BATCH 16
#define CDIM 256
#define HW 9216
#define RDIM 32
#define KC 32
#define LDST 68
#define SPLITS 16
#define KSLAB (HW / SPLITS)   /* 576 */
#define KCH 64                /* k-columns staged per chunk */
#define NCHUNK (KSLAB / KCH)  /* 9 */

typedef __attribute__((ext_vector_type(8))) short short8;
typedef __attribute__((ext_vector_type(4))) float f32x4;

__device__ __forceinline__ unsigned short bf16_rne(float x) {
    union { float f; unsigned u; } a; a.f = x;
    return (unsigned short)((a.u + 0x7fffu + ((a.u >> 16) & 1u)) >> 16);
}
__device__ __forceinline__ float bf16_to_f(unsigned short h) {
    union { unsigned u; float f; } a; a.u = ((unsigned)h) << 16;
    return a.f;
}
// XOR-swizzled LDS element index for a [256][64] bf16 tile (row stride 128 B).
// Toggles byte bits 4..6 so 16 rows at the same k hit distinct 16B slots.
__device__ __forceinline__ int swzidx(int row, int k) {
    int byte = row * 128 + k * 2;
    byte ^= ((row & 7) << 4) ^ ((row & 8) << 1);
    return byte >> 1;
}

// ---------------- K1: energy partial = v v^T (split-K, bf16 hi/lo MFMA) ----------
// grid (SPLITS, BATCH), block 1024 = 16 waves in a 4x4 grid; each wave owns a
// 64x64 output patch (16 MFMA tiles of 16x16, K-step 32). hi/lo split bf16:
// energy ~ hh + hl + lh (near-fp32 precision at bf16 MFMA rate).
// Also accumulates row sums into `pooled` (fuses the old pool_kernel).
__global__ __launch_bounds__(1024) void gram_kernel(const float* __restrict__ x,
                                                    float* __restrict__ energy,
                                                    float* __restrict__ pooled) {
    int split = blockIdx.x;
    int b     = blockIdx.y;
    const float* v = x + (size_t)b * CDIM * HW;
    int kbase0 = split * KSLAB;

    __shared__ short ldsH[CDIM * KCH];   // 32 KB
    __shared__ short ldsL[CDIM * KCH];   // 32 KB

    int t    = threadIdx.x;
    int row  = t >> 2;          // 0..255: each thread stages one channel row
    int kq   = t & 3;           // quarter of the 64-wide k chunk
    int lane = t & 63;
    int wave = t >> 6;
    int wr   = wave >> 2, wc = wave & 3;
    int lhi  = lane >> 4;       // 0..3
    int llo  = lane & 15;

    const float4* vrow = (const float4*)(v + (size_t)row * HW);

    f32x4 acc[4][4];
    #pragma unroll
    for (int i = 0; i < 4; ++i)
        #pragma unroll
        for (int j = 0; j < 4; ++j)
            acc[i][j] = (f32x4){0.f, 0.f, 0.f, 0.f};

    float psum = 0.f;

    for (int ch = 0; ch < NCHUNK; ++ch) {
        int kb = kbase0 + ch * KCH;
        float4 f[4];
        #pragma unroll
        for (int s = 0; s < 4; ++s) f[s] = vrow[(kb >> 2) + kq * 4 + s];
        #pragma unroll
        for (int s = 0; s < 4; ++s) psum += f[s].x + f[s].y + f[s].z + f[s].w;

        // convert 16 floats -> 2 groups of (8 hi, 8 lo) bf16
        short8 h8[2], l8[2];
        #pragma unroll
        for (int g = 0; g < 2; ++g) {
            float vals[8] = { f[2*g].x, f[2*g].y, f[2*g].z, f[2*g].w,
                              f[2*g+1].x, f[2*g+1].y, f[2*g+1].z, f[2*g+1].w };
            #pragma unroll
            for (int j = 0; j < 8; ++j) {
                unsigned short h = bf16_rne(vals[j]);
                float rem = vals[j] - bf16_to_f(h);
                h8[g][j] = (short)h;
                l8[g][j] = (short)bf16_rne(rem);
            }
        }
        __syncthreads();   // previous chunk's readers done
        #pragma unroll
        for (int g = 0; g < 2; ++g) {
            int idx = swzidx(row, kq * 16 + g * 8);
            *(short8*)&ldsH[idx] = h8[g];
            *(short8*)&ldsL[idx] = l8[g];
        }
        __syncthreads();   // tile staged

        #pragma unroll
        for (int ks = 0; ks < 2; ++ks) {
            int kf = ks * 32 + lhi * 8;
            short8 Ah[4], Al[4], Bh[4], Bl[4];
            #pragma unroll
            for (int rb = 0; rb < 4; ++rb) {
                int idx = swzidx(wr * 64 + rb * 16 + llo, kf);
                Ah[rb] = *(const short8*)&ldsH[idx];
                Al[rb] = *(const short8*)&ldsL[idx];
            }
            #pragma unroll
            for (int cb = 0; cb < 4; ++cb) {
                int idx = swzidx(wc * 64 + cb * 16 + llo, kf);
                Bh[cb] = *(const short8*)&ldsH[idx];
                Bl[cb] = *(const short8*)&ldsL[idx];
            }
            #pragma unroll
            for (int rb = 0; rb < 4; ++rb)
                #pragma unroll
                for (int cb = 0; cb < 4; ++cb) {
                    acc[rb][cb] = __builtin_amdgcn_mfma_f32_16x16x32_bf16(Ah[rb], Bh[cb], acc[rb][cb], 0, 0, 0);
                    acc[rb][cb] = __builtin_amdgcn_mfma_f32_16x16x32_bf16(Ah[rb], Bl[cb], acc[rb][cb], 0, 0, 0);
                    acc[rb][cb] = __builtin_amdgcn_mfma_f32_16x16x32_bf16(Al[rb], Bh[cb], acc[rb][cb], 0, 0, 0);
                }
        }
    }

    // fused pooling: combine the 4 k-quarters of each row, one atomic per row
    psum += __shfl_xor(psum, 1);
    psum += __shfl_xor(psum, 2);
    if (kq == 0) atomicAdd(&pooled[b * CDIM + row], psum);

    // accumulate energy partials. C/D layout: col = lane&15, row = (lane>>4)*4 + reg
    #pragma unroll
    for (int rb = 0; rb < 4; ++rb) {
        int r0 = wr * 64 + rb * 16 + lhi * 4;
        #pragma unroll
        for (int cb = 0; cb < 4; ++cb) {
            int c0 = wc * 64 + cb * 16 + llo;
            #pragma unroll
            for (int reg = 0; reg < 4; ++reg)
                atomicAdd(&energy[((size_t)b * CDIM + r0 + reg) * CDIM + c0], acc[rb][cb][reg]);
        }
    }
}

// ---------------- K2: SE MLP -> sigmoid gate (pooled holds SUMS, scale by 1/HW) ----
__global__ __launch_bounds__(256) void se_kernel(const float* __restrict__ pooled,
                                                 const float* __restrict__ w1,
                                                 const float* __restrict__ b1,
                                                 const float* __restrict__ w2,
                                                 const float* __restrict__ b2,
                                                 float* __restrict__ gate) {
    int b = blockIdx.x;
    int t = threadIdx.x;
    __shared__ float p[CDIM];
    __shared__ float hid[RDIM];
    p[t] = pooled[b * CDIM + t] * (1.0f / HW);
    __syncthreads();
    if (t < RDIM) {
        float s = b1[t];
        const float* wr = w1 + t * CDIM;
        for (int k = 0; k < CDIM; ++k) s = fmaf(wr[k], p[k], s);
        hid[t] = s > 0.f ? s : 0.f;
    }
    __syncthreads();
    float s = b2[t];
    const float* wr = w2 + t * RDIM;
    #pragma unroll
    for (int k = 0; k < RDIM; ++k) s = fmaf(wr[k], hid[k], s);
    gate[b * CDIM + t] = 1.0f / (1.0f + expf(-s));
}

// ---------------- K3: row softmax of (rowmax - energy), in place ----------------
// softmax(max - e) == exp(rowmin - e) / sum  (shift invariance)
__global__ __launch_bounds__(256) void softmax_kernel(float* __restrict__ energy) {
    int row = blockIdx.x;
    float* e = energy + (size_t)row * CDIM;
    int t = threadIdx.x;
    float val = e[t];

    float m = val;
    for (int off = 32; off > 0; off >>= 1) m = fminf(m, __shfl_down(m, off));
    __shared__ float redm[4];
    if ((t & 63) == 0) redm[t >> 6] = m;
    __syncthreads();
    float rowmin = fminf(fminf(redm[0], redm[1]), fminf(redm[2], redm[3]));

    float p = expf(rowmin - val);
    float s = p;
    for (int off = 32; off > 0; off >>= 1) s += __shfl_down(s, off);
    __shared__ float reds[4];
    if ((t & 63) == 0) reds[t >> 6] = s;
    __syncthreads();
    float tot = reds[0] + reds[1] + reds[2] + reds[3];
    e[t] = p / tot;
}

// ---------------- K4: out = gamma * gate * (att @ v) + x (fp32, unchanged) -------
__global__ __launch_bounds__(256) void out_kernel(const float* __restrict__ att,
                                                  const float* __restrict__ x,
                                                  const float* __restrict__ gate,
                                                  const float* __restrict__ gammap,
                                                  float* __restrict__ out) {
    int n0 = blockIdx.x * 64;
    int c0 = blockIdx.y * 64;
    int b  = blockIdx.z;
    const float* v    = x   + (size_t)b * CDIM * HW;
    const float* attb = att + (size_t)b * CDIM * CDIM;

    __shared__ float As[KC][LDST];
    __shared__ float Bs[KC][LDST];

    int t  = threadIdx.x;
    int tx = t & 15, ty = t >> 4;
    int lrow = t >> 3;
    int lk4  = (t & 7) * 4;
    int bk   = t >> 4;
    int bn4  = (t & 15) * 4;

    float acc[4][4] = {};

    for (int k0 = 0; k0 < CDIM; k0 += KC) {
        float4 a0 = *(const float4*)&attb[(size_t)(c0 + lrow)      * CDIM + k0 + lk4];
        float4 a1 = *(const float4*)&attb[(size_t)(c0 + lrow + 32) * CDIM + k0 + lk4];
        float4 b0 = *(const float4*)&v[(size_t)(k0 + bk)      * HW + n0 + bn4];
        float4 b1 = *(const float4*)&v[(size_t)(k0 + bk + 16) * HW + n0 + bn4];
        __syncthreads();
        As[lk4+0][lrow] = a0.x; As[lk4+1][lrow] = a0.y; As[lk4+2][lrow] = a0.z; As[lk4+3][lrow] = a0.w;
        As[lk4+0][lrow+32] = a1.x; As[lk4+1][lrow+32] = a1.y; As[lk4+2][lrow+32] = a1.z; As[lk4+3][lrow+32] = a1.w;
        *(float4*)&Bs[bk][bn4]      = b0;
        *(float4*)&Bs[bk + 16][bn4] = b1;
        __syncthreads();
        #pragma unroll
        for (int k = 0; k < KC; ++k) {
            float af[4], bf[4];
            *(float4*)af = *(const float4*)&As[k][ty * 4];
            *(float4*)bf = *(const float4*)&Bs[k][tx * 4];
            #pragma unroll
            for (int i = 0; i < 4; ++i)
                #pragma unroll
                for (int j = 0; j < 4; ++j)
                    acc[i][j] = fmaf(af[i], bf[j], acc[i][j]);
        }
    }

    float gm = gammap[0];
    #pragma unroll
    for (int i = 0; i < 4; ++i) {
        int c = c0 + ty * 4 + i;
        float g = gm * gate[b * CDIM + c];
        size_t base = ((size_t)b * CDIM + c) * HW + n0 + tx * 4;
        float4 xv = *(const float4*)&x[base];
        float4 o;
        o.x = fmaf(acc[i][0], g, xv.x);
        o.y = fmaf(acc[i][1], g, xv.y);
        o.z = fmaf(acc[i][2], g, xv.z);
        o.w = fmaf(acc[i][3], g, xv.w);
        *(float4*)&out[base] = o;
    }
}

extern "C" void kernel_launch(void* const* d_in, const int* in_sizes, int n_in,
                              void* d_out, int out_size, void* d_ws, size_t ws_size,
                              hipStream_t stream) {
    const float* x     = (const float*)d_in[0];
    const float* gamma = (const float*)d_in[1];
    const float* w1    = (const float*)d_in[2];
    const float* b1    = (const float*)d_in[3];
    const float* w2    = (const float*)d_in[4];
    const float* b2    = (const float*)d_in[5];
    float* out = (float*)d_out;

    float* energy = (float*)d_ws;                                // B*C*C = 4 MB
    float* pooled = energy + (size_t)BATCH * CDIM * CDIM;        // B*C
    float* gate   = pooled + BATCH * CDIM;                       // B*C

    hipMemsetAsync(energy, 0, (size_t)BATCH * CDIM * CDIM * sizeof(float), stream);
    hipMemsetAsync(pooled, 0, (size_t)BATCH * CDIM * sizeof(float), stream);
    gram_kernel<<<dim3(SPLITS, BATCH), 1024, 0, stream>>>(x, energy, pooled);
    se_kernel<<<BATCH, 256, 0, stream>>>(pooled, w1, b1, w2, b2, gate);
    softmax_kernel<<<BATCH * CDIM, 256, 0, stream>>>(energy);
    out_kernel<<<dim3(HW / 64, CDIM / 64, BATCH), 256, 0, stream>>>(energy, x, gate, gamma, out);
}

// Round 3
// 250.364 us; speedup vs baseline: 2.2130x; 1.4367x over previous
//
#include <hip/hip_runtime.h>
#include <math.h>

#define BATCH 16
#define CDIM 256
#define HW 9216
#define RDIM 32
#define SPLITS 16
#define KSLAB (HW / SPLITS)   /* 576 */
#define KCH 64                /* k-columns staged per chunk (gram) */
#define NCHUNK (KSLAB / KCH)  /* 9 */

#define BN 256                /* out_kernel n-tile */
#define BK 64                 /* out_kernel k-chunk */
#define BOFF 32768            /* ldsB byte offset inside shared block */

typedef __attribute__((ext_vector_type(8))) short short8;
typedef __attribute__((ext_vector_type(4))) short short4_t;
typedef __attribute__((ext_vector_type(4))) float f32x4;

__device__ __forceinline__ unsigned short bf16_rne(float x) {
    union { float f; unsigned u; } a; a.f = x;
    return (unsigned short)((a.u + 0x7fffu + ((a.u >> 16) & 1u)) >> 16);
}
__device__ __forceinline__ float bf16_to_f(unsigned short h) {
    union { unsigned u; float f; } a; a.u = ((unsigned)h) << 16;
    return a.f;
}
__device__ __forceinline__ unsigned pack2(float lo, float hi) {
    return (unsigned)bf16_rne(lo) | ((unsigned)bf16_rne(hi) << 16);
}

// gram-kernel swizzle (round-1, verified conflict-free per 8-lane group)
__device__ __forceinline__ int swzidx(int row, int k) {
    int byte = row * 128 + k * 2;
    byte ^= ((row & 7) << 4) ^ ((row & 8) << 1);
    return byte >> 1;
}
// out-kernel swizzle: conflict-free for BOTH u32 transpose-writes (row bits 2-4)
// and b128 frag reads (row bits 0-2). Row stride 128 B, XOR into byte bits 4-6.
__device__ __forceinline__ int bofs(int row, int k) {
    return (((row) << 7) | ((k) << 1)) ^ (((row ^ (row >> 2)) & 7) << 4);
}

// ---------------- K1: energy partial = v v^T (split-K, bf16 hi/lo MFMA) ----------
__global__ __launch_bounds__(1024) void gram_kernel(const float* __restrict__ x,
                                                    float* __restrict__ energy,
                                                    float* __restrict__ pooled) {
    int split = blockIdx.x;
    int b     = blockIdx.y;
    const float* v = x + (size_t)b * CDIM * HW;
    int kbase0 = split * KSLAB;

    __shared__ short ldsH[CDIM * KCH];   // 32 KB
    __shared__ short ldsL[CDIM * KCH];   // 32 KB

    int t    = threadIdx.x;
    int row  = t >> 2;
    int kq   = t & 3;
    int lane = t & 63;
    int wave = t >> 6;
    int wr   = wave >> 2, wc = wave & 3;
    int lhi  = lane >> 4;
    int llo  = lane & 15;

    const float4* vrow = (const float4*)(v + (size_t)row * HW);

    f32x4 acc[4][4];
    #pragma unroll
    for (int i = 0; i < 4; ++i)
        #pragma unroll
        for (int j = 0; j < 4; ++j)
            acc[i][j] = (f32x4){0.f, 0.f, 0.f, 0.f};

    float psum = 0.f;

    for (int ch = 0; ch < NCHUNK; ++ch) {
        int kb = kbase0 + ch * KCH;
        float4 f[4];
        #pragma unroll
        for (int s = 0; s < 4; ++s) f[s] = vrow[(kb >> 2) + kq * 4 + s];
        #pragma unroll
        for (int s = 0; s < 4; ++s) psum += f[s].x + f[s].y + f[s].z + f[s].w;

        short8 h8[2], l8[2];
        #pragma unroll
        for (int g = 0; g < 2; ++g) {
            float vals[8] = { f[2*g].x, f[2*g].y, f[2*g].z, f[2*g].w,
                              f[2*g+1].x, f[2*g+1].y, f[2*g+1].z, f[2*g+1].w };
            #pragma unroll
            for (int j = 0; j < 8; ++j) {
                unsigned short h = bf16_rne(vals[j]);
                float rem = vals[j] - bf16_to_f(h);
                h8[g][j] = (short)h;
                l8[g][j] = (short)bf16_rne(rem);
            }
        }
        __syncthreads();
        #pragma unroll
        for (int g = 0; g < 2; ++g) {
            int idx = swzidx(row, kq * 16 + g * 8);
            *(short8*)&ldsH[idx] = h8[g];
            *(short8*)&ldsL[idx] = l8[g];
        }
        __syncthreads();

        #pragma unroll
        for (int ks = 0; ks < 2; ++ks) {
            int kf = ks * 32 + lhi * 8;
            short8 Ah[4], Al[4], Bh[4], Bl[4];
            #pragma unroll
            for (int rb = 0; rb < 4; ++rb) {
                int idx = swzidx(wr * 64 + rb * 16 + llo, kf);
                Ah[rb] = *(const short8*)&ldsH[idx];
                Al[rb] = *(const short8*)&ldsL[idx];
            }
            #pragma unroll
            for (int cb = 0; cb < 4; ++cb) {
                int idx = swzidx(wc * 64 + cb * 16 + llo, kf);
                Bh[cb] = *(const short8*)&ldsH[idx];
                Bl[cb] = *(const short8*)&ldsL[idx];
            }
            #pragma unroll
            for (int rb = 0; rb < 4; ++rb)
                #pragma unroll
                for (int cb = 0; cb < 4; ++cb) {
                    acc[rb][cb] = __builtin_amdgcn_mfma_f32_16x16x32_bf16(Ah[rb], Bh[cb], acc[rb][cb], 0, 0, 0);
                    acc[rb][cb] = __builtin_amdgcn_mfma_f32_16x16x32_bf16(Ah[rb], Bl[cb], acc[rb][cb], 0, 0, 0);
                    acc[rb][cb] = __builtin_amdgcn_mfma_f32_16x16x32_bf16(Al[rb], Bh[cb], acc[rb][cb], 0, 0, 0);
                }
        }
    }

    psum += __shfl_xor(psum, 1);
    psum += __shfl_xor(psum, 2);
    if (kq == 0) atomicAdd(&pooled[b * CDIM + row], psum);

    #pragma unroll
    for (int rb = 0; rb < 4; ++rb) {
        int r0 = wr * 64 + rb * 16 + lhi * 4;
        #pragma unroll
        for (int cb = 0; cb < 4; ++cb) {
            int c0 = wc * 64 + cb * 16 + llo;
            #pragma unroll
            for (int reg = 0; reg < 4; ++reg)
                atomicAdd(&energy[((size_t)b * CDIM + r0 + reg) * CDIM + c0], acc[rb][cb][reg]);
        }
    }
}

// ---------------- K2: SE MLP -> sigmoid gate ----------------
__global__ __launch_bounds__(256) void se_kernel(const float* __restrict__ pooled,
                                                 const float* __restrict__ w1,
                                                 const float* __restrict__ b1,
                                                 const float* __restrict__ w2,
                                                 const float* __restrict__ b2,
                                                 float* __restrict__ gate) {
    int b = blockIdx.x;
    int t = threadIdx.x;
    __shared__ float p[CDIM];
    __shared__ float hid[RDIM];
    p[t] = pooled[b * CDIM + t] * (1.0f / HW);
    __syncthreads();
    if (t < RDIM) {
        float s = b1[t];
        const float* wr = w1 + t * CDIM;
        for (int k = 0; k < CDIM; ++k) s = fmaf(wr[k], p[k], s);
        hid[t] = s > 0.f ? s : 0.f;
    }
    __syncthreads();
    float s = b2[t];
    const float* wr = w2 + t * RDIM;
    #pragma unroll
    for (int k = 0; k < RDIM; ++k) s = fmaf(wr[k], hid[k], s);
    gate[b * CDIM + t] = 1.0f / (1.0f + expf(-s));
}

// ---------------- K3: row softmax of (rowmax - energy), in place ----------------
__global__ __launch_bounds__(256) void softmax_kernel(float* __restrict__ energy) {
    int row = blockIdx.x;
    float* e = energy + (size_t)row * CDIM;
    int t = threadIdx.x;
    float val = e[t];

    float m = val;
    for (int off = 32; off > 0; off >>= 1) m = fminf(m, __shfl_down(m, off));
    __shared__ float redm[4];
    if ((t & 63) == 0) redm[t >> 6] = m;
    __syncthreads();
    float rowmin = fminf(fminf(redm[0], redm[1]), fminf(redm[2], redm[3]));

    float p = expf(rowmin - val);
    float s = p;
    for (int off = 32; off > 0; off >>= 1) s += __shfl_down(s, off);
    __shared__ float reds[4];
    if ((t & 63) == 0) reds[t >> 6] = s;
    __syncthreads();
    float tot = reds[0] + reds[1] + reds[2] + reds[3];
    e[t] = p / tot;
}

// ---------------- K4: out = gamma * gate * (att @ v) + x  (bf16 MFMA) ----------
// grid (HW/BN, BATCH), block 1024 = 16 waves (4x4), wave tile 64c x 64n.
// A = att[256 c][k] bf16 in LDS; B = v^T staged [256 n][64 dd] bf16 via
// pair-packed u32 transpose-writes. K loop: 4 chunks of 64.
__global__ __launch_bounds__(1024) void out_kernel(const float* __restrict__ att,
                                                   const float* __restrict__ x,
                                                   const float* __restrict__ gate,
                                                   const float* __restrict__ gammap,
                                                   float* __restrict__ out) {
    __shared__ __align__(16) char lds[65536];   // A: 32KB @0, B: 32KB @BOFF

    const int t    = threadIdx.x;
    const int lane = t & 63;
    const int wave = t >> 6;
    const int wr   = wave >> 2, wc = wave & 3;
    const int lhi  = lane >> 4, llo = lane & 15;
    const int nblk = blockIdx.x * BN;
    const int b    = blockIdx.y;

    const float* v    = x   + (size_t)b * CDIM * HW;
    const float* attb = att + (size_t)b * CDIM * CDIM;

    f32x4 acc[4][4];
    #pragma unroll
    for (int i = 0; i < 4; ++i)
        #pragma unroll
        for (int j = 0; j < 4; ++j)
            acc[i][j] = (f32x4){0.f, 0.f, 0.f, 0.f};

    // staging registers
    float4 va0[2], va1[2], aa[4];

    // ---- load chunk k0 into regs ----
    auto load_chunk = [&](int k0) {
        #pragma unroll
        for (int i = 0; i < 2; ++i) {
            int dd0 = 2 * (wave + 16 * i);
            const float* r0 = v + (size_t)(k0 + dd0) * HW + nblk + lane * 4;
            va0[i] = *(const float4*)r0;
            va1[i] = *(const float4*)(r0 + HW);
        }
        #pragma unroll
        for (int i = 0; i < 4; ++i) {
            int c = (t >> 4) + 64 * i;
            aa[i] = *(const float4*)&attb[(size_t)c * CDIM + k0 + (t & 15) * 4];
        }
    };

    load_chunk(0);

    for (int ch = 0; ch < 4; ++ch) {
        __syncthreads();   // previous chunk's readers done
        // ---- write staged regs to LDS ----
        #pragma unroll
        for (int i = 0; i < 2; ++i) {
            int dd0 = 2 * (wave + 16 * i);
            const float* f0 = (const float*)&va0[i];
            const float* f1 = (const float*)&va1[i];
            #pragma unroll
            for (int j = 0; j < 4; ++j) {
                int n = lane * 4 + j;
                *(unsigned*)(lds + BOFF + bofs(n, dd0)) = pack2(f0[j], f1[j]);
            }
        }
        #pragma unroll
        for (int i = 0; i < 4; ++i) {
            int c = (t >> 4) + 64 * i;
            const float* fa = (const float*)&aa[i];
            short4_t h = { (short)bf16_rne(fa[0]), (short)bf16_rne(fa[1]),
                           (short)bf16_rne(fa[2]), (short)bf16_rne(fa[3]) };
            *(short4_t*)(lds + bofs(c, (t & 15) * 4)) = h;
        }
        __syncthreads();   // tile staged

        if (ch < 3) load_chunk((ch + 1) * BK);   // prefetch under MFMA

        // ---- compute: 2 k-steps of 32, 16 MFMA tiles per wave ----
        #pragma unroll
        for (int ks = 0; ks < 2; ++ks) {
            int kb = ks * 32 + lhi * 8;
            short8 Af[4], Bf[4];
            #pragma unroll
            for (int rb = 0; rb < 4; ++rb)
                Af[rb] = *(const short8*)(lds + bofs(wr * 64 + rb * 16 + llo, kb));
            #pragma unroll
            for (int cb = 0; cb < 4; ++cb)
                Bf[cb] = *(const short8*)(lds + BOFF + bofs(wc * 64 + cb * 16 + llo, kb));
            #pragma unroll
            for (int rb = 0; rb < 4; ++rb)
                #pragma unroll
                for (int cb = 0; cb < 4; ++cb)
                    acc[rb][cb] = __builtin_amdgcn_mfma_f32_16x16x32_bf16(Af[rb], Bf[cb], acc[rb][cb], 0, 0, 0);
        }
    }

    // ---- epilogue: out = acc * (gamma*gate[c]) + x ----
    float gm = gammap[0];
    #pragma unroll
    for (int rb = 0; rb < 4; ++rb) {
        #pragma unroll
        for (int r = 0; r < 4; ++r) {
            int c = wr * 64 + rb * 16 + lhi * 4 + r;
            float g = gm * gate[b * CDIM + c];
            size_t rowbase = ((size_t)b * CDIM + c) * HW + nblk;
            #pragma unroll
            for (int cb = 0; cb < 4; ++cb) {
                int n = wc * 64 + cb * 16 + llo;
                out[rowbase + n] = fmaf(acc[rb][cb][r], g, x[rowbase + n]);
            }
        }
    }
}

extern "C" void kernel_launch(void* const* d_in, const int* in_sizes, int n_in,
                              void* d_out, int out_size, void* d_ws, size_t ws_size,
                              hipStream_t stream) {
    const float* x     = (const float*)d_in[0];
    const float* gamma = (const float*)d_in[1];
    const float* w1    = (const float*)d_in[2];
    const float* b1    = (const float*)d_in[3];
    const float* w2    = (const float*)d_in[4];
    const float* b2    = (const float*)d_in[5];
    float* out = (float*)d_out;

    float* energy = (float*)d_ws;
    float* pooled = energy + (size_t)BATCH * CDIM * CDIM;
    float* gate   = pooled + BATCH * CDIM;

    hipMemsetAsync(energy, 0, (size_t)BATCH * CDIM * CDIM * sizeof(float), stream);
    hipMemsetAsync(pooled, 0, (size_t)BATCH * CDIM * sizeof(float), stream);
    gram_kernel<<<dim3(SPLITS, BATCH), 1024, 0, stream>>>(x, energy, pooled);
    se_kernel<<<BATCH, 256, 0, stream>>>(pooled, w1, b1, w2, b2, gate);
    softmax_kernel<<<BATCH * CDIM, 256, 0, stream>>>(energy);
    out_kernel<<<dim3(HW / BN, BATCH), 1024, 0, stream>>>(energy, x, gate, gamma, out);
}